// Round 1
// baseline (1620.765 us; speedup 1.0000x reference)
//
#include <hip/hip_runtime.h>
#include <hip/hip_bf16.h>

// Problem constants
#define B_   8
#define C_   64
#define H_   256
#define W_   256
#define HW_  65536      // H*W
#define CHW  4194304    // C*H*W (per-batch stride of x / projections)
#define F_   16384      // attention feature dim = CI*W
#define ROWS 256        // attention rows = H
#define KSPLIT 16
#define KCH  1024       // F_ / KSPLIT

// ---------------------------------------------------------------------------
// ws layout (floats):
//   theta : [0,          33554432)
//   phi   : [33554432,   67108864)
//   g     : [67108864,  100663296)
//   yt    : [0,          33554432)   (reuses theta, dead after fmat)
//   fpart : [100663296, 109051904)   B*KSPLIT*256*256 = 8388608
//   At    : [109051904, 109576192)   B*256*256        =  524288
// total = 109576192 floats = 438.3 MB
// ---------------------------------------------------------------------------

// ---- projections: out[b,o,p] = bias[o] + sum_c w[o,c]*in[b,c,p] -----------
__global__ __launch_bounds__(256) void proj2_kernel(
    const float* __restrict__ x,
    const float* __restrict__ w_phi, const float* __restrict__ b_phi,
    const float* __restrict__ w_g,   const float* __restrict__ b_g,
    float* __restrict__ phi, float* __restrict__ g)
{
    int blk = blockIdx.x;
    int b = blk >> 8;                       // 256 blocks per batch
    int p = ((blk & 255) << 8) + threadIdx.x;
    size_t base = (size_t)b * CHW + p;
    float xv[64];
#pragma unroll
    for (int c = 0; c < 64; ++c) xv[c] = x[base + (size_t)c * HW_];
    for (int o = 0; o < 64; ++o) {
        float ap = b_phi[o];                // uniform -> scalar loads
        float ag = b_g[o];
#pragma unroll
        for (int c = 0; c < 64; ++c) {
            ap = fmaf(w_phi[(o << 6) + c], xv[c], ap);
            ag = fmaf(w_g[(o << 6) + c],  xv[c], ag);
        }
        phi[base + (size_t)o * HW_] = ap;
        g[base + (size_t)o * HW_]   = ag;
    }
}

__global__ __launch_bounds__(256) void proj1_kernel(
    const float* __restrict__ in,
    const float* __restrict__ w, const float* __restrict__ bias,
    float* __restrict__ out)
{
    int blk = blockIdx.x;
    int b = blk >> 8;
    int p = ((blk & 255) << 8) + threadIdx.x;
    size_t base = (size_t)b * CHW + p;
    float xv[64];
#pragma unroll
    for (int c = 0; c < 64; ++c) xv[c] = in[base + (size_t)c * HW_];
    for (int o = 0; o < 64; ++o) {
        float a = bias[o];
#pragma unroll
        for (int c = 0; c < 64; ++c) a = fmaf(w[(o << 6) + c], xv[c], a);
        out[base + (size_t)o * HW_] = a;
    }
}

// ---- f partial GEMM: fpart[b,ks,j,i] += sum_{k in chunk} phi[b,j,k]*theta[b,i,k]
// grid: b(8) x jt(2) x it(2) x ks(16) = 512 blocks, 128x128 tile
__global__ __launch_bounds__(256) void fmat_kernel(
    const float* __restrict__ theta, const float* __restrict__ phi,
    float* __restrict__ fpart)
{
    __shared__ float sP[16][132];   // [k][j]  (132: 16B-aligned rows, depad banks)
    __shared__ float sT[16][132];   // [k][i]
    int blk = blockIdx.x;
    int ks = blk & 15;
    int it = (blk >> 4) & 1;
    int jt = (blk >> 5) & 1;
    int b  = blk >> 6;
    int k0 = ks * KCH;
    const float* phiB = phi   + (size_t)b * CHW + (size_t)(jt * 128) * F_ + k0;
    const float* theB = theta + (size_t)b * CHW + (size_t)(it * 128) * F_ + k0;
    int tid = threadIdx.x;
    int ti = tid & 15, tj = tid >> 4;
    int lr = tid >> 1;              // row 0..127
    int lc = (tid & 1) * 8;         // col 0 or 8

    float acc[8][8];
#pragma unroll
    for (int a = 0; a < 8; ++a)
#pragma unroll
        for (int q = 0; q < 8; ++q) acc[a][q] = 0.f;

    for (int kb = 0; kb < KCH; kb += 16) {
        const float* ps = phiB + (size_t)lr * F_ + kb + lc;
        const float* ts = theB + (size_t)lr * F_ + kb + lc;
        float4 p0 = *(const float4*)ps;
        float4 p1 = *(const float4*)(ps + 4);
        float4 t0 = *(const float4*)ts;
        float4 t1 = *(const float4*)(ts + 4);
        __syncthreads();
        sP[lc + 0][lr] = p0.x; sP[lc + 1][lr] = p0.y; sP[lc + 2][lr] = p0.z; sP[lc + 3][lr] = p0.w;
        sP[lc + 4][lr] = p1.x; sP[lc + 5][lr] = p1.y; sP[lc + 6][lr] = p1.z; sP[lc + 7][lr] = p1.w;
        sT[lc + 0][lr] = t0.x; sT[lc + 1][lr] = t0.y; sT[lc + 2][lr] = t0.z; sT[lc + 3][lr] = t0.w;
        sT[lc + 4][lr] = t1.x; sT[lc + 5][lr] = t1.y; sT[lc + 6][lr] = t1.z; sT[lc + 7][lr] = t1.w;
        __syncthreads();
#pragma unroll
        for (int k = 0; k < 16; ++k) {
            float av[8], bv[8];
            float4 a0 = *(const float4*)&sP[k][tj * 8];
            float4 a1 = *(const float4*)&sP[k][tj * 8 + 4];
            float4 b0 = *(const float4*)&sT[k][ti * 8];
            float4 b1 = *(const float4*)&sT[k][ti * 8 + 4];
            av[0]=a0.x; av[1]=a0.y; av[2]=a0.z; av[3]=a0.w;
            av[4]=a1.x; av[5]=a1.y; av[6]=a1.z; av[7]=a1.w;
            bv[0]=b0.x; bv[1]=b0.y; bv[2]=b0.z; bv[3]=b0.w;
            bv[4]=b1.x; bv[5]=b1.y; bv[6]=b1.z; bv[7]=b1.w;
#pragma unroll
            for (int jj = 0; jj < 8; ++jj)
#pragma unroll
                for (int ii = 0; ii < 8; ++ii)
                    acc[jj][ii] = fmaf(av[jj], bv[ii], acc[jj][ii]);
        }
    }
    size_t obase = (size_t)(b * KSPLIT + ks) * 65536;
#pragma unroll
    for (int jj = 0; jj < 8; ++jj) {
        int j = jt * 128 + tj * 8 + jj;
        int i = it * 128 + ti * 8;
        float4 v0 = {acc[jj][0], acc[jj][1], acc[jj][2], acc[jj][3]};
        float4 v1 = {acc[jj][4], acc[jj][5], acc[jj][6], acc[jj][7]};
        *(float4*)&fpart[obase + (size_t)j * 256 + i]     = v0;
        *(float4*)&fpart[obase + (size_t)j * 256 + i + 4] = v1;
    }
}

// ---- softmax over i per (b,j): At[b,j,i] = softmax_i( sum_ks fpart ) -------
__global__ __launch_bounds__(256) void softmax_kernel(
    const float* __restrict__ fpart, float* __restrict__ At)
{
    __shared__ float red[8];
    int blk = blockIdx.x;               // b*256 + j
    int b = blk >> 8, j = blk & 255;
    int i = threadIdx.x;
    float v = 0.f;
#pragma unroll
    for (int ks = 0; ks < KSPLIT; ++ks)
        v += fpart[(size_t)(b * KSPLIT + ks) * 65536 + (size_t)j * 256 + i];
    float m = v;
#pragma unroll
    for (int off = 32; off >= 1; off >>= 1) m = fmaxf(m, __shfl_xor(m, off, 64));
    if ((i & 63) == 0) red[i >> 6] = m;
    __syncthreads();
    m = fmaxf(fmaxf(red[0], red[1]), fmaxf(red[2], red[3]));
    float e = __expf(v - m);
    float s = e;
#pragma unroll
    for (int off = 32; off >= 1; off >>= 1) s += __shfl_xor(s, off, 64);
    if ((i & 63) == 0) red[4 + (i >> 6)] = s;
    __syncthreads();
    s = red[4] + red[5] + red[6] + red[7];
    At[(size_t)b * 65536 + (size_t)j * 256 + i] = e / s;
}

// ---- y transposed: yt[b,F,i] = sum_j g[b,j,F] * At[b,j,i] ------------------
// grid: b(8) x Ft(128) x it(2) = 2048 blocks, tile 128(F) x 128(i), K=256
__global__ __launch_bounds__(256) void ymat_kernel(
    const float* __restrict__ g, const float* __restrict__ At,
    float* __restrict__ yt)
{
    __shared__ float sG[16][132];   // [k(j)][F_local]
    __shared__ float sA[16][132];   // [k(j)][i_local]
    int blk = blockIdx.x;
    int it = blk & 1;
    int Ft = (blk >> 1) & 127;
    int b  = blk >> 8;
    const float* gB = g  + (size_t)b * CHW   + Ft * 128;
    const float* aB = At + (size_t)b * 65536 + it * 128;
    int tid = threadIdx.x;
    int tn = tid & 15, tm = tid >> 4;
    int lr = tid >> 4;              // k row 0..15
    int lc = (tid & 15) * 8;        // col 0..120

    float acc[8][8];
#pragma unroll
    for (int a = 0; a < 8; ++a)
#pragma unroll
        for (int q = 0; q < 8; ++q) acc[a][q] = 0.f;

    for (int kb = 0; kb < 256; kb += 16) {
        const float* gs = gB + (size_t)(kb + lr) * F_  + lc;
        const float* as = aB + (size_t)(kb + lr) * 256 + lc;
        float4 g0 = *(const float4*)gs;
        float4 g1 = *(const float4*)(gs + 4);
        float4 a0 = *(const float4*)as;
        float4 a1 = *(const float4*)(as + 4);
        __syncthreads();
        *(float4*)&sG[lr][lc]     = g0;
        *(float4*)&sG[lr][lc + 4] = g1;
        *(float4*)&sA[lr][lc]     = a0;
        *(float4*)&sA[lr][lc + 4] = a1;
        __syncthreads();
#pragma unroll
        for (int k = 0; k < 16; ++k) {
            float av[8], bv[8];
            float4 m0 = *(const float4*)&sG[k][tm * 8];
            float4 m1 = *(const float4*)&sG[k][tm * 8 + 4];
            float4 n0 = *(const float4*)&sA[k][tn * 8];
            float4 n1 = *(const float4*)&sA[k][tn * 8 + 4];
            av[0]=m0.x; av[1]=m0.y; av[2]=m0.z; av[3]=m0.w;
            av[4]=m1.x; av[5]=m1.y; av[6]=m1.z; av[7]=m1.w;
            bv[0]=n0.x; bv[1]=n0.y; bv[2]=n0.z; bv[3]=n0.w;
            bv[4]=n1.x; bv[5]=n1.y; bv[6]=n1.z; bv[7]=n1.w;
#pragma unroll
            for (int mm = 0; mm < 8; ++mm)
#pragma unroll
                for (int nn = 0; nn < 8; ++nn)
                    acc[mm][nn] = fmaf(av[mm], bv[nn], acc[mm][nn]);
        }
    }
#pragma unroll
    for (int mm = 0; mm < 8; ++mm) {
        size_t Fg = (size_t)(Ft * 128 + tm * 8 + mm);
        int i = it * 128 + tn * 8;
        float4 v0 = {acc[mm][0], acc[mm][1], acc[mm][2], acc[mm][3]};
        float4 v1 = {acc[mm][4], acc[mm][5], acc[mm][6], acc[mm][7]};
        *(float4*)&yt[(size_t)b * CHW + Fg * 256 + i]     = v0;
        *(float4*)&yt[(size_t)b * CHW + Fg * 256 + i + 4] = v1;
    }
}

// ---- final conv + residual: out[b,o,h2,w2] = bW[o]+x + sum_c2 wW[o,c2]*yt[b,c2*256+h2,w2]
__global__ __launch_bounds__(256) void out_kernel(
    const float* __restrict__ yt, const float* __restrict__ x,
    const float* __restrict__ wW, const float* __restrict__ bW,
    float* __restrict__ out)
{
    int blk = blockIdx.x;
    int b = blk >> 8, h2 = blk & 255;
    int t = threadIdx.x;                 // w2
    float yv[64];
#pragma unroll
    for (int c2 = 0; c2 < 64; ++c2)
        yv[c2] = yt[(size_t)b * CHW + (size_t)(c2 * 256 + h2) * 256 + t];
    for (int o = 0; o < 64; ++o) {
        float acc = bW[o];
#pragma unroll
        for (int c2 = 0; c2 < 64; ++c2)
            acc = fmaf(wW[(o << 6) + c2], yv[c2], acc);
        size_t idx = ((size_t)(b * 64 + o) * 256 + h2) * 256 + t;
        out[idx] = acc + x[idx];
    }
}

extern "C" void kernel_launch(void* const* d_in, const int* in_sizes, int n_in,
                              void* d_out, int out_size, void* d_ws, size_t ws_size,
                              hipStream_t stream) {
    const float* x   = (const float*)d_in[0];
    const float* ref = (const float*)d_in[1];
    const float* w_g = (const float*)d_in[2];
    const float* b_g = (const float*)d_in[3];
    const float* w_t = (const float*)d_in[4];
    const float* b_t = (const float*)d_in[5];
    const float* w_p = (const float*)d_in[6];
    const float* b_p = (const float*)d_in[7];
    const float* w_W = (const float*)d_in[8];
    const float* b_W = (const float*)d_in[9];
    float* out = (float*)d_out;
    float* ws  = (float*)d_ws;

    float* theta = ws;
    float* phi   = ws + 33554432;
    float* g     = ws + 67108864;
    float* yt    = ws;                   // reuse theta (dead after fmat)
    float* fpart = ws + 100663296;
    float* At    = ws + 109051904 - 8388608 + 8388608;  // = ws + 109051904

    proj2_kernel<<<2048, 256, 0, stream>>>(x, w_p, b_p, w_g, b_g, phi, g);
    proj1_kernel<<<2048, 256, 0, stream>>>(ref, w_t, b_t, theta);
    fmat_kernel<<<512, 256, 0, stream>>>(theta, phi, fpart);
    softmax_kernel<<<2048, 256, 0, stream>>>(fpart, At);
    ymat_kernel<<<2048, 256, 0, stream>>>(g, At, yt);
    out_kernel<<<2048, 256, 0, stream>>>(yt, x, w_W, b_W, out);
}

// Round 2
// 1035.723 us; speedup vs baseline: 1.5649x; 1.5649x over previous
//
#include <hip/hip_runtime.h>
#include <hip/hip_bf16.h>

// Problem constants
#define B_   8
#define C_   64
#define H_   256
#define W_   256
#define HW_  65536      // H*W
#define CHW  4194304    // C*H*W (per-batch stride of x / projections)
#define F_   16384      // attention feature dim = CI*W
#define KSPLIT 16
#define KCH  1024       // F_ / KSPLIT

// ---------------------------------------------------------------------------
// ws layout (floats):
//   theta : [0,          33554432)
//   phi   : [33554432,   67108864)
//   g     : [67108864,  100663296)
//   yt    : [0,          33554432)   (reuses theta, dead after fmat)
//   fpart : [100663296, 109051904)   B*KSPLIT*256*256 = 8388608
//   At    : aliases fpart slice ks=0 (per-batch stride 16*65536) — written by
//           softmax AFTER it reads the slice, same thread/same address.
//   wt4   : [109051904, 109068288)   4 transposed 64x64 weight matrices
// total = 109068288 floats = 436.3 MB (<= round-1 footprint, known to fit)
// ---------------------------------------------------------------------------

// ---- prep: transpose the four 64x64 weight matrices: wt[c][o] = w[o][c] ----
__global__ __launch_bounds__(256) void prep_kernel(
    const float* __restrict__ w_phi, const float* __restrict__ w_g,
    const float* __restrict__ w_theta, const float* __restrict__ w_W,
    float* __restrict__ wt4)
{
    int tid = threadIdx.x;
    const float* src[4] = {w_phi, w_g, w_theta, w_W};
#pragma unroll
    for (int m = 0; m < 4; ++m) {
        float* dst = wt4 + m * 4096;
        const float* s = src[m];
#pragma unroll
        for (int r = 0; r < 16; ++r) {
            int idx = r * 256 + tid;
            int o = idx >> 6, c = idx & 63;
            dst[c * 64 + o] = s[idx];
        }
    }
}

// ---- g64: out[b,o,p0+p] = bias[o] + sum_c wt[c][o]*in[b,c,p0+p] (+resid) ---
// block tile: 64 o x 256 pixels; thread micro-tile 8o x 8pix.
// thread (to=tid>>5 in [0,8), tp=tid&31):
//   o  in {to*4+0..3} u {32+to*4+0..3}
//   p  in {tp*4+0..3} u {128+tp*4+0..3}
// All LDS compute reads are consecutive-float4-per-lane -> conflict-free.
template<bool RESID>
__global__ __launch_bounds__(256) void g64_kernel(
    const float* __restrict__ in, const float* __restrict__ wt,
    const float* __restrict__ bias, const float* __restrict__ resid,
    float* __restrict__ outp)
{
    __shared__ float sX[16][260];
    __shared__ float sW[16][68];
    int blk = blockIdx.x;
    int b = blk >> 8;
    int p0 = (blk & 255) << 8;
    size_t base = (size_t)b * CHW + p0;
    int tid = threadIdx.x;
    int tp = tid & 31, to = tid >> 5;
    int srow = tid >> 4;            // 0..15 staging row
    int scol = (tid & 15) * 4;      // 0..60 staging col (floats)

    float acc[8][8];
#pragma unroll
    for (int i = 0; i < 8; ++i)
#pragma unroll
        for (int j = 0; j < 8; ++j) acc[i][j] = 0.f;

    for (int c0 = 0; c0 < 64; c0 += 16) {
        float4 xr[4];
#pragma unroll
        for (int r = 0; r < 4; ++r)
            xr[r] = *(const float4*)&in[base + (size_t)(c0 + srow) * HW_ + scol + r * 64];
        float4 wr = *(const float4*)&wt[(c0 + srow) * 64 + scol];
        __syncthreads();
#pragma unroll
        for (int r = 0; r < 4; ++r)
            *(float4*)&sX[srow][scol + r * 64] = xr[r];
        *(float4*)&sW[srow][scol] = wr;
        __syncthreads();
#pragma unroll
        for (int k = 0; k < 16; ++k) {
            float4 x0 = *(const float4*)&sX[k][tp * 4];
            float4 x1 = *(const float4*)&sX[k][128 + tp * 4];
            float4 w0 = *(const float4*)&sW[k][to * 4];
            float4 w1 = *(const float4*)&sW[k][32 + to * 4];
            float xv[8] = {x0.x, x0.y, x0.z, x0.w, x1.x, x1.y, x1.z, x1.w};
            float wv[8] = {w0.x, w0.y, w0.z, w0.w, w1.x, w1.y, w1.z, w1.w};
#pragma unroll
            for (int oo = 0; oo < 8; ++oo)
#pragma unroll
                for (int pp = 0; pp < 8; ++pp)
                    acc[oo][pp] = fmaf(wv[oo], xv[pp], acc[oo][pp]);
        }
    }
#pragma unroll
    for (int oo = 0; oo < 8; ++oo) {
        int o = (oo < 4) ? (to * 4 + oo) : (32 + to * 4 + (oo - 4));
        float bv = bias[o];
        size_t ob0 = base + (size_t)o * HW_ + tp * 4;
        size_t ob1 = ob0 + 128;
        float4 v0 = {acc[oo][0] + bv, acc[oo][1] + bv, acc[oo][2] + bv, acc[oo][3] + bv};
        float4 v1 = {acc[oo][4] + bv, acc[oo][5] + bv, acc[oo][6] + bv, acc[oo][7] + bv};
        if (RESID) {
            float4 r0 = *(const float4*)&resid[ob0];
            float4 r1 = *(const float4*)&resid[ob1];
            v0.x += r0.x; v0.y += r0.y; v0.z += r0.z; v0.w += r0.w;
            v1.x += r1.x; v1.y += r1.y; v1.z += r1.z; v1.w += r1.w;
        }
        *(float4*)&outp[ob0] = v0;
        *(float4*)&outp[ob1] = v1;
    }
}

// ---- f partial GEMM: fpart[b,ks,j,i] += sum_{k in chunk} phi[b,j,k]*theta[b,i,k]
__global__ __launch_bounds__(256) void fmat_kernel(
    const float* __restrict__ theta, const float* __restrict__ phi,
    float* __restrict__ fpart)
{
    __shared__ float sP[16][132];   // [k][j]
    __shared__ float sT[16][132];   // [k][i]
    int blk = blockIdx.x;
    int ks = blk & 15;
    int it = (blk >> 4) & 1;
    int jt = (blk >> 5) & 1;
    int b  = blk >> 6;
    int k0 = ks * KCH;
    const float* phiB = phi   + (size_t)b * CHW + (size_t)(jt * 128) * F_ + k0;
    const float* theB = theta + (size_t)b * CHW + (size_t)(it * 128) * F_ + k0;
    int tid = threadIdx.x;
    int ti = tid & 15, tj = tid >> 4;
    int lr = tid >> 1;
    int lc = (tid & 1) * 8;

    float acc[8][8];
#pragma unroll
    for (int a = 0; a < 8; ++a)
#pragma unroll
        for (int q = 0; q < 8; ++q) acc[a][q] = 0.f;

    for (int kb = 0; kb < KCH; kb += 16) {
        const float* ps = phiB + (size_t)lr * F_ + kb + lc;
        const float* ts = theB + (size_t)lr * F_ + kb + lc;
        float4 p0 = *(const float4*)ps;
        float4 p1 = *(const float4*)(ps + 4);
        float4 t0 = *(const float4*)ts;
        float4 t1 = *(const float4*)(ts + 4);
        __syncthreads();
        sP[lc + 0][lr] = p0.x; sP[lc + 1][lr] = p0.y; sP[lc + 2][lr] = p0.z; sP[lc + 3][lr] = p0.w;
        sP[lc + 4][lr] = p1.x; sP[lc + 5][lr] = p1.y; sP[lc + 6][lr] = p1.z; sP[lc + 7][lr] = p1.w;
        sT[lc + 0][lr] = t0.x; sT[lc + 1][lr] = t0.y; sT[lc + 2][lr] = t0.z; sT[lc + 3][lr] = t0.w;
        sT[lc + 4][lr] = t1.x; sT[lc + 5][lr] = t1.y; sT[lc + 6][lr] = t1.z; sT[lc + 7][lr] = t1.w;
        __syncthreads();
#pragma unroll
        for (int k = 0; k < 16; ++k) {
            float av[8], bv[8];
            float4 a0 = *(const float4*)&sP[k][tj * 8];
            float4 a1 = *(const float4*)&sP[k][tj * 8 + 4];
            float4 b0 = *(const float4*)&sT[k][ti * 8];
            float4 b1 = *(const float4*)&sT[k][ti * 8 + 4];
            av[0]=a0.x; av[1]=a0.y; av[2]=a0.z; av[3]=a0.w;
            av[4]=a1.x; av[5]=a1.y; av[6]=a1.z; av[7]=a1.w;
            bv[0]=b0.x; bv[1]=b0.y; bv[2]=b0.z; bv[3]=b0.w;
            bv[4]=b1.x; bv[5]=b1.y; bv[6]=b1.z; bv[7]=b1.w;
#pragma unroll
            for (int jj = 0; jj < 8; ++jj)
#pragma unroll
                for (int ii = 0; ii < 8; ++ii)
                    acc[jj][ii] = fmaf(av[jj], bv[ii], acc[jj][ii]);
        }
    }
    size_t obase = (size_t)(b * KSPLIT + ks) * 65536;
#pragma unroll
    for (int jj = 0; jj < 8; ++jj) {
        int j = jt * 128 + tj * 8 + jj;
        int i = it * 128 + ti * 8;
        float4 v0 = {acc[jj][0], acc[jj][1], acc[jj][2], acc[jj][3]};
        float4 v1 = {acc[jj][4], acc[jj][5], acc[jj][6], acc[jj][7]};
        *(float4*)&fpart[obase + (size_t)j * 256 + i]     = v0;
        *(float4*)&fpart[obase + (size_t)j * 256 + i + 4] = v1;
    }
}

// ---- softmax over i per (b,j); writes At into fpart slice ks=0 -------------
__global__ __launch_bounds__(256) void softmax_kernel(float* __restrict__ fpart)
{
    __shared__ float red[8];
    int blk = blockIdx.x;               // b*256 + j
    int b = blk >> 8, j = blk & 255;
    int i = threadIdx.x;
    float v = 0.f;
#pragma unroll
    for (int ks = 0; ks < KSPLIT; ++ks)
        v += fpart[(size_t)(b * KSPLIT + ks) * 65536 + (size_t)j * 256 + i];
    float m = v;
#pragma unroll
    for (int off = 32; off >= 1; off >>= 1) m = fmaxf(m, __shfl_xor(m, off, 64));
    if ((i & 63) == 0) red[i >> 6] = m;
    __syncthreads();
    m = fmaxf(fmaxf(red[0], red[1]), fmaxf(red[2], red[3]));
    float e = __expf(v - m);
    float s = e;
#pragma unroll
    for (int off = 32; off >= 1; off >>= 1) s += __shfl_xor(s, off, 64);
    if ((i & 63) == 0) red[4 + (i >> 6)] = s;
    __syncthreads();
    s = red[4] + red[5] + red[6] + red[7];
    // overwrite slice ks=0 (this thread already consumed its read of it)
    fpart[(size_t)(b * KSPLIT) * 65536 + (size_t)j * 256 + i] = e / s;
}

// ---- y transposed: yt[b,F,i] = sum_j g[b,j,F] * At[b,j,i] ------------------
__global__ __launch_bounds__(256) void ymat_kernel(
    const float* __restrict__ g, const float* __restrict__ At,
    float* __restrict__ yt)
{
    __shared__ float sG[16][132];
    __shared__ float sA[16][132];
    int blk = blockIdx.x;
    int it = blk & 1;
    int Ft = (blk >> 1) & 127;
    int b  = blk >> 8;
    const float* gB = g  + (size_t)b * CHW + Ft * 128;
    const float* aB = At + (size_t)b * (KSPLIT * 65536) + it * 128;  // slice ks=0
    int tid = threadIdx.x;
    int tn = tid & 15, tm = tid >> 4;
    int lr = tid >> 4;
    int lc = (tid & 15) * 8;

    float acc[8][8];
#pragma unroll
    for (int a = 0; a < 8; ++a)
#pragma unroll
        for (int q = 0; q < 8; ++q) acc[a][q] = 0.f;

    for (int kb = 0; kb < 256; kb += 16) {
        const float* gs = gB + (size_t)(kb + lr) * F_  + lc;
        const float* as = aB + (size_t)(kb + lr) * 256 + lc;
        float4 g0 = *(const float4*)gs;
        float4 g1 = *(const float4*)(gs + 4);
        float4 a0 = *(const float4*)as;
        float4 a1 = *(const float4*)(as + 4);
        __syncthreads();
        *(float4*)&sG[lr][lc]     = g0;
        *(float4*)&sG[lr][lc + 4] = g1;
        *(float4*)&sA[lr][lc]     = a0;
        *(float4*)&sA[lr][lc + 4] = a1;
        __syncthreads();
#pragma unroll
        for (int k = 0; k < 16; ++k) {
            float av[8], bv[8];
            float4 m0 = *(const float4*)&sG[k][tm * 8];
            float4 m1 = *(const float4*)&sG[k][tm * 8 + 4];
            float4 n0 = *(const float4*)&sA[k][tn * 8];
            float4 n1 = *(const float4*)&sA[k][tn * 8 + 4];
            av[0]=m0.x; av[1]=m0.y; av[2]=m0.z; av[3]=m0.w;
            av[4]=m1.x; av[5]=m1.y; av[6]=m1.z; av[7]=m1.w;
            bv[0]=n0.x; bv[1]=n0.y; bv[2]=n0.z; bv[3]=n0.w;
            bv[4]=n1.x; bv[5]=n1.y; bv[6]=n1.z; bv[7]=n1.w;
#pragma unroll
            for (int mm = 0; mm < 8; ++mm)
#pragma unroll
                for (int nn = 0; nn < 8; ++nn)
                    acc[mm][nn] = fmaf(av[mm], bv[nn], acc[mm][nn]);
        }
    }
#pragma unroll
    for (int mm = 0; mm < 8; ++mm) {
        size_t Fg = (size_t)(Ft * 128 + tm * 8 + mm);
        int i = it * 128 + tn * 8;
        float4 v0 = {acc[mm][0], acc[mm][1], acc[mm][2], acc[mm][3]};
        float4 v1 = {acc[mm][4], acc[mm][5], acc[mm][6], acc[mm][7]};
        *(float4*)&yt[(size_t)b * CHW + Fg * 256 + i]     = v0;
        *(float4*)&yt[(size_t)b * CHW + Fg * 256 + i + 4] = v1;
    }
}

extern "C" void kernel_launch(void* const* d_in, const int* in_sizes, int n_in,
                              void* d_out, int out_size, void* d_ws, size_t ws_size,
                              hipStream_t stream) {
    const float* x   = (const float*)d_in[0];
    const float* ref = (const float*)d_in[1];
    const float* w_g = (const float*)d_in[2];
    const float* b_g = (const float*)d_in[3];
    const float* w_t = (const float*)d_in[4];
    const float* b_t = (const float*)d_in[5];
    const float* w_p = (const float*)d_in[6];
    const float* b_p = (const float*)d_in[7];
    const float* w_W = (const float*)d_in[8];
    const float* b_W = (const float*)d_in[9];
    float* out = (float*)d_out;
    float* ws  = (float*)d_ws;

    float* theta = ws;
    float* phi   = ws + 33554432;
    float* g     = ws + 67108864;
    float* yt    = ws;                    // reuse theta (dead after fmat)
    float* fpart = ws + 100663296;
    float* At    = fpart;                 // slice ks=0, per-batch stride 16*65536
    float* wt4   = ws + 109051904;
    float* wt_p  = wt4;
    float* wt_g  = wt4 + 4096;
    float* wt_t  = wt4 + 8192;
    float* wt_W  = wt4 + 12288;

    prep_kernel<<<1, 256, 0, stream>>>(w_p, w_g, w_t, w_W, wt4);
    g64_kernel<false><<<2048, 256, 0, stream>>>(x,   wt_p, b_p, nullptr, phi);
    g64_kernel<false><<<2048, 256, 0, stream>>>(x,   wt_g, b_g, nullptr, g);
    g64_kernel<false><<<2048, 256, 0, stream>>>(ref, wt_t, b_t, nullptr, theta);
    fmat_kernel<<<512, 256, 0, stream>>>(theta, phi, fpart);
    softmax_kernel<<<2048, 256, 0, stream>>>(fpart);
    ymat_kernel<<<2048, 256, 0, stream>>>(g, At, yt);
    g64_kernel<true><<<2048, 256, 0, stream>>>(yt, wt_W, b_W, x, out);
}

// Round 3
// 885.471 us; speedup vs baseline: 1.8304x; 1.1697x over previous
//
#include <hip/hip_runtime.h>
#include <hip/hip_bf16.h>

// Problem constants
#define B_   8
#define C_   64
#define H_   256
#define W_   256
#define HW_  65536      // H*W
#define CHW  4194304    // C*H*W (per-batch stride of x / projections)
#define F_   16384      // attention feature dim = CI*W
#define KSPLIT 16
#define KCH  1024       // F_ / KSPLIT

typedef __attribute__((ext_vector_type(8)))  short  short8;   // 8 bf16 = 4 VGPRs
typedef __attribute__((ext_vector_type(4)))  float  floatx4;  // MFMA acc

// float -> bf16 bits, round-to-nearest-even
__device__ __forceinline__ unsigned short f2bf(float v) {
    unsigned int u = __builtin_bit_cast(unsigned int, v);
    unsigned int r = u + 0x7fffu + ((u >> 16) & 1u);
    return (unsigned short)(r >> 16);
}
__device__ __forceinline__ float bf2f(unsigned short h) {
    unsigned int u = ((unsigned int)h) << 16;
    return __builtin_bit_cast(float, u);
}

// ---------------------------------------------------------------------------
// ws layout (floats):
//   theta : [0,          33554432)
//   phi   : [33554432,   67108864)
//   g     : [67108864,  100663296)
//   yt    : [0,          33554432)   (reuses theta, dead after fmat)
//   fpart : [100663296, 109051904)   B*KSPLIT*256*256 = 8388608
//   At    : aliases fpart slice ks=0
//   wt4   : [109051904, 109068288)
// ---------------------------------------------------------------------------

// ---- prep: transpose the four 64x64 weight matrices ------------------------
__global__ __launch_bounds__(256) void prep_kernel(
    const float* __restrict__ w_phi, const float* __restrict__ w_g,
    const float* __restrict__ w_theta, const float* __restrict__ w_W,
    float* __restrict__ wt4)
{
    int tid = threadIdx.x;
    const float* src[4] = {w_phi, w_g, w_theta, w_W};
#pragma unroll
    for (int m = 0; m < 4; ++m) {
        float* dst = wt4 + m * 4096;
        const float* s = src[m];
#pragma unroll
        for (int r = 0; r < 16; ++r) {
            int idx = r * 256 + tid;
            int o = idx >> 6, c = idx & 63;
            dst[c * 64 + o] = s[idx];
        }
    }
}

// ---- g64: out[b,o,p0+p] = bias[o] + sum_c wt[c][o]*in[b,c,p0+p] (+resid) ---
template<bool RESID>
__global__ __launch_bounds__(256) void g64_kernel(
    const float* __restrict__ in, const float* __restrict__ wt,
    const float* __restrict__ bias, const float* __restrict__ resid,
    float* __restrict__ outp)
{
    __shared__ float sX[16][260];
    __shared__ float sW[16][68];
    int blk = blockIdx.x;
    int b = blk >> 8;
    int p0 = (blk & 255) << 8;
    size_t base = (size_t)b * CHW + p0;
    int tid = threadIdx.x;
    int tp = tid & 31, to = tid >> 5;
    int srow = tid >> 4;
    int scol = (tid & 15) * 4;

    float acc[8][8];
#pragma unroll
    for (int i = 0; i < 8; ++i)
#pragma unroll
        for (int j = 0; j < 8; ++j) acc[i][j] = 0.f;

    for (int c0 = 0; c0 < 64; c0 += 16) {
        float4 xr[4];
#pragma unroll
        for (int r = 0; r < 4; ++r)
            xr[r] = *(const float4*)&in[base + (size_t)(c0 + srow) * HW_ + scol + r * 64];
        float4 wr = *(const float4*)&wt[(c0 + srow) * 64 + scol];
        __syncthreads();
#pragma unroll
        for (int r = 0; r < 4; ++r)
            *(float4*)&sX[srow][scol + r * 64] = xr[r];
        *(float4*)&sW[srow][scol] = wr;
        __syncthreads();
#pragma unroll
        for (int k = 0; k < 16; ++k) {
            float4 x0 = *(const float4*)&sX[k][tp * 4];
            float4 x1 = *(const float4*)&sX[k][128 + tp * 4];
            float4 w0 = *(const float4*)&sW[k][to * 4];
            float4 w1 = *(const float4*)&sW[k][32 + to * 4];
            float xv[8] = {x0.x, x0.y, x0.z, x0.w, x1.x, x1.y, x1.z, x1.w};
            float wv[8] = {w0.x, w0.y, w0.z, w0.w, w1.x, w1.y, w1.z, w1.w};
#pragma unroll
            for (int oo = 0; oo < 8; ++oo)
#pragma unroll
                for (int pp = 0; pp < 8; ++pp)
                    acc[oo][pp] = fmaf(wv[oo], xv[pp], acc[oo][pp]);
        }
    }
#pragma unroll
    for (int oo = 0; oo < 8; ++oo) {
        int o = (oo < 4) ? (to * 4 + oo) : (32 + to * 4 + (oo - 4));
        float bv = bias[o];
        size_t ob0 = base + (size_t)o * HW_ + tp * 4;
        size_t ob1 = ob0 + 128;
        float4 v0 = {acc[oo][0] + bv, acc[oo][1] + bv, acc[oo][2] + bv, acc[oo][3] + bv};
        float4 v1 = {acc[oo][4] + bv, acc[oo][5] + bv, acc[oo][6] + bv, acc[oo][7] + bv};
        if (RESID) {
            float4 r0 = *(const float4*)&resid[ob0];
            float4 r1 = *(const float4*)&resid[ob1];
            v0.x += r0.x; v0.y += r0.y; v0.z += r0.z; v0.w += r0.w;
            v1.x += r1.x; v1.y += r1.y; v1.z += r1.z; v1.w += r1.w;
        }
        *(float4*)&outp[ob0] = v0;
        *(float4*)&outp[ob1] = v1;
    }
}

// ---- fmat (MFMA split-bf16): fpart[b,ks,j,i] = sum_k phi[j,k]*theta[i,k] ---
// f = phi . theta^T via D = A.B: A[m=j][k] = phi_row, B[k][n=i] = theta_row.
// Split fp32 = hi(bf16) + lo(bf16 residual); 3 MFMA passes share one acc.
// Block: 128(j) x 128(i), K-chunk 1024 (KSPLIT=16). 4 waves, 64x64 each.
__global__ __launch_bounds__(256) void fmat_kernel(
    const float* __restrict__ theta, const float* __restrict__ phi,
    float* __restrict__ fpart)
{
    __shared__ unsigned short sPh[128 * 32];  // [j_local][k32] bf16 hi
    __shared__ unsigned short sPl[128 * 32];
    __shared__ unsigned short sTh[128 * 32];  // [i_local][k32]
    __shared__ unsigned short sTl[128 * 32];

    int blk = blockIdx.x;
    int ks = blk & 15;
    int it = (blk >> 4) & 1;
    int jt = (blk >> 5) & 1;
    int b  = blk >> 6;
    int k0 = ks * KCH;
    int i0 = it * 128, j0 = jt * 128;
    const float* phiB = phi   + (size_t)b * CHW + (size_t)j0 * F_ + k0;
    const float* theB = theta + (size_t)b * CHW + (size_t)i0 * F_ + k0;

    int tid  = threadIdx.x;
    int wave = tid >> 6;
    int lane = tid & 63;
    int wj = wave >> 1, wi = wave & 1;
    int frow = lane & 15;          // fragment row (m or n)
    int fkq  = lane >> 4;          // fragment k-quad (8 bf16 each)

    // staging coords: 64B-contiguous per 4 lanes
    int sr = tid >> 2;             // base row 0..63
    int sk = (tid & 3) * 4;        // base k 0..12

    floatx4 acc[4][4];
#pragma unroll
    for (int a = 0; a < 4; ++a)
#pragma unroll
        for (int q = 0; q < 4; ++q) acc[a][q] = (floatx4){0.f, 0.f, 0.f, 0.f};

    for (int kk = 0; kk < KCH; kk += 32) {
        // ---- stage: fp32 -> (hi,lo) bf16 into LDS -----------------------
        float4 pv[4], tv[4];
#pragma unroll
        for (int q = 0; q < 4; ++q) {
            int row = sr + (q & 1) * 64;
            int ko  = sk + (q >> 1) * 16;
            pv[q] = *(const float4*)&phiB[(size_t)row * F_ + kk + ko];
            tv[q] = *(const float4*)&theB[(size_t)row * F_ + kk + ko];
        }
        __syncthreads();
#pragma unroll
        for (int q = 0; q < 4; ++q) {
            int row = sr + (q & 1) * 64;
            int ko  = sk + (q >> 1) * 16;
            int idx = row * 32 + ko;
            float pf[4] = {pv[q].x, pv[q].y, pv[q].z, pv[q].w};
            float tf[4] = {tv[q].x, tv[q].y, tv[q].z, tv[q].w};
            ushort4 ph, pl, th, tl;
            unsigned short* php = (unsigned short*)&ph;
            unsigned short* plp = (unsigned short*)&pl;
            unsigned short* thp = (unsigned short*)&th;
            unsigned short* tlp = (unsigned short*)&tl;
#pragma unroll
            for (int e = 0; e < 4; ++e) {
                unsigned short h = f2bf(pf[e]);
                php[e] = h;
                plp[e] = f2bf(pf[e] - bf2f(h));
                h = f2bf(tf[e]);
                thp[e] = h;
                tlp[e] = f2bf(tf[e] - bf2f(h));
            }
            *(ushort4*)&sPh[idx] = ph;
            *(ushort4*)&sPl[idx] = pl;
            *(ushort4*)&sTh[idx] = th;
            *(ushort4*)&sTl[idx] = tl;
        }
        __syncthreads();

        // ---- fragments + MFMA ------------------------------------------
        short8 bh[4], bl[4];
#pragma unroll
        for (int ii = 0; ii < 4; ++ii) {
            int ridx = (wi * 64 + ii * 16 + frow) * 32 + fkq * 8;
            bh[ii] = *(const short8*)&sTh[ridx];
            bl[ii] = *(const short8*)&sTl[ridx];
        }
#pragma unroll
        for (int jj = 0; jj < 4; ++jj) {
            int ridx = (wj * 64 + jj * 16 + frow) * 32 + fkq * 8;
            short8 ah = *(const short8*)&sPh[ridx];
            short8 al = *(const short8*)&sPl[ridx];
#pragma unroll
            for (int ii = 0; ii < 4; ++ii) {
                acc[jj][ii] = __builtin_amdgcn_mfma_f32_16x16x32_bf16(ah, bh[ii], acc[jj][ii], 0, 0, 0);
                acc[jj][ii] = __builtin_amdgcn_mfma_f32_16x16x32_bf16(ah, bl[ii], acc[jj][ii], 0, 0, 0);
                acc[jj][ii] = __builtin_amdgcn_mfma_f32_16x16x32_bf16(al, bh[ii], acc[jj][ii], 0, 0, 0);
            }
        }
    }

    // ---- store: D row=j_local, col=i_local; col=lane&15, row=(lane>>4)*4+reg
    size_t obase = (size_t)(b * KSPLIT + ks) * 65536;
#pragma unroll
    for (int jj = 0; jj < 4; ++jj) {
#pragma unroll
        for (int ii = 0; ii < 4; ++ii) {
            int i = i0 + wi * 64 + ii * 16 + frow;
#pragma unroll
            for (int r = 0; r < 4; ++r) {
                int j = j0 + wj * 64 + jj * 16 + fkq * 4 + r;
                fpart[obase + (size_t)j * 256 + i] = acc[jj][ii][r];
            }
        }
    }
}

// ---- softmax over i per (b,j); writes At into fpart slice ks=0 -------------
__global__ __launch_bounds__(256) void softmax_kernel(float* __restrict__ fpart)
{
    __shared__ float red[8];
    int blk = blockIdx.x;
    int b = blk >> 8, j = blk & 255;
    int i = threadIdx.x;
    float v = 0.f;
#pragma unroll
    for (int ks = 0; ks < KSPLIT; ++ks)
        v += fpart[(size_t)(b * KSPLIT + ks) * 65536 + (size_t)j * 256 + i];
    float m = v;
#pragma unroll
    for (int off = 32; off >= 1; off >>= 1) m = fmaxf(m, __shfl_xor(m, off, 64));
    if ((i & 63) == 0) red[i >> 6] = m;
    __syncthreads();
    m = fmaxf(fmaxf(red[0], red[1]), fmaxf(red[2], red[3]));
    float e = __expf(v - m);
    float s = e;
#pragma unroll
    for (int off = 32; off >= 1; off >>= 1) s += __shfl_xor(s, off, 64);
    if ((i & 63) == 0) red[4 + (i >> 6)] = s;
    __syncthreads();
    s = red[4] + red[5] + red[6] + red[7];
    fpart[(size_t)(b * KSPLIT) * 65536 + (size_t)j * 256 + i] = e / s;
}

// ---- y transposed: yt[b,F,i] = sum_j g[b,j,F] * At[b,j,i] ------------------
__global__ __launch_bounds__(256) void ymat_kernel(
    const float* __restrict__ g, const float* __restrict__ At,
    float* __restrict__ yt)
{
    __shared__ float sG[16][132];
    __shared__ float sA[16][132];
    int blk = blockIdx.x;
    int it = blk & 1;
    int Ft = (blk >> 1) & 127;
    int b  = blk >> 8;
    const float* gB = g  + (size_t)b * CHW + Ft * 128;
    const float* aB = At + (size_t)b * (KSPLIT * 65536) + it * 128;
    int tid = threadIdx.x;
    int tn = tid & 15, tm = tid >> 4;
    int lr = tid >> 4;
    int lc = (tid & 15) * 8;

    float acc[8][8];
#pragma unroll
    for (int a = 0; a < 8; ++a)
#pragma unroll
        for (int q = 0; q < 8; ++q) acc[a][q] = 0.f;

    for (int kb = 0; kb < 256; kb += 16) {
        const float* gs = gB + (size_t)(kb + lr) * F_  + lc;
        const float* as = aB + (size_t)(kb + lr) * 256 + lc;
        float4 g0 = *(const float4*)gs;
        float4 g1 = *(const float4*)(gs + 4);
        float4 a0 = *(const float4*)as;
        float4 a1 = *(const float4*)(as + 4);
        __syncthreads();
        *(float4*)&sG[lr][lc]     = g0;
        *(float4*)&sG[lr][lc + 4] = g1;
        *(float4*)&sA[lr][lc]     = a0;
        *(float4*)&sA[lr][lc + 4] = a1;
        __syncthreads();
#pragma unroll
        for (int k = 0; k < 16; ++k) {
            float av[8], bv[8];
            float4 m0 = *(const float4*)&sG[k][tm * 8];
            float4 m1 = *(const float4*)&sG[k][tm * 8 + 4];
            float4 n0 = *(const float4*)&sA[k][tn * 8];
            float4 n1 = *(const float4*)&sA[k][tn * 8 + 4];
            av[0]=m0.x; av[1]=m0.y; av[2]=m0.z; av[3]=m0.w;
            av[4]=m1.x; av[5]=m1.y; av[6]=m1.z; av[7]=m1.w;
            bv[0]=n0.x; bv[1]=n0.y; bv[2]=n0.z; bv[3]=n0.w;
            bv[4]=n1.x; bv[5]=n1.y; bv[6]=n1.z; bv[7]=n1.w;
#pragma unroll
            for (int mm = 0; mm < 8; ++mm)
#pragma unroll
                for (int nn = 0; nn < 8; ++nn)
                    acc[mm][nn] = fmaf(av[mm], bv[nn], acc[mm][nn]);
        }
    }
#pragma unroll
    for (int mm = 0; mm < 8; ++mm) {
        size_t Fg = (size_t)(Ft * 128 + tm * 8 + mm);
        int i = it * 128 + tn * 8;
        float4 v0 = {acc[mm][0], acc[mm][1], acc[mm][2], acc[mm][3]};
        float4 v1 = {acc[mm][4], acc[mm][5], acc[mm][6], acc[mm][7]};
        *(float4*)&yt[(size_t)b * CHW + Fg * 256 + i]     = v0;
        *(float4*)&yt[(size_t)b * CHW + Fg * 256 + i + 4] = v1;
    }
}

extern "C" void kernel_launch(void* const* d_in, const int* in_sizes, int n_in,
                              void* d_out, int out_size, void* d_ws, size_t ws_size,
                              hipStream_t stream) {
    const float* x   = (const float*)d_in[0];
    const float* ref = (const float*)d_in[1];
    const float* w_g = (const float*)d_in[2];
    const float* b_g = (const float*)d_in[3];
    const float* w_t = (const float*)d_in[4];
    const float* b_t = (const float*)d_in[5];
    const float* w_p = (const float*)d_in[6];
    const float* b_p = (const float*)d_in[7];
    const float* w_W = (const float*)d_in[8];
    const float* b_W = (const float*)d_in[9];
    float* out = (float*)d_out;
    float* ws  = (float*)d_ws;

    float* theta = ws;
    float* phi   = ws + 33554432;
    float* g     = ws + 67108864;
    float* yt    = ws;                    // reuse theta (dead after fmat)
    float* fpart = ws + 100663296;
    float* At    = fpart;                 // slice ks=0
    float* wt4   = ws + 109051904;
    float* wt_p  = wt4;
    float* wt_g  = wt4 + 4096;
    float* wt_t  = wt4 + 8192;
    float* wt_W  = wt4 + 12288;

    prep_kernel<<<1, 256, 0, stream>>>(w_p, w_g, w_t, w_W, wt4);
    g64_kernel<false><<<2048, 256, 0, stream>>>(x,   wt_p, b_p, nullptr, phi);
    g64_kernel<false><<<2048, 256, 0, stream>>>(x,   wt_g, b_g, nullptr, g);
    g64_kernel<false><<<2048, 256, 0, stream>>>(ref, wt_t, b_t, nullptr, theta);
    fmat_kernel<<<512, 256, 0, stream>>>(theta, phi, fpart);
    softmax_kernel<<<2048, 256, 0, stream>>>(fpart);
    ymat_kernel<<<2048, 256, 0, stream>>>(g, At, yt);
    g64_kernel<true><<<2048, 256, 0, stream>>>(yt, wt_W, b_W, x, out);
}